// Round 14
// baseline (49.166 us; speedup 1.0000x reference)
//
#include <hip/hip_runtime.h>

#define H 384
#define W 384
#define C 19
#define NB 4
#define HP 382               // H - K + 1
#define HW (H * W)
#define CHW (C * HW)
#define TOTAL_TERMS 47279376.0f   // NB * 81 * HP*HP

#define NBLOCKS 1152         // 147456 groups / 128

// number of kernel-offsets a in [0,2] with 0 <= a+d <= 2 and 0 <= p-a <= HP-1
__device__ __forceinline__ int multv(int p, int d) {
    int lo = max(max(0, -d), p - (HP - 1));
    int hi = min(min(2, 2 - d), p);
    return max(0, hi - lo + 1);
}

__device__ __forceinline__ float bce_fast(float x, float y) {
    // max(x,0) - x*y + log1p(exp(-|x|)), fast-math variant
    float t = __expf(-fabsf(x));
    return fmaxf(x, 0.0f) - x * y + __logf(1.0f + t);
}

// R12 skeleton (depth-2, 3-slot register pipeline — 28.4 µs proven) with ONE
// change: halo loads trimmed to float2 (fewer L1 bytes AND fewer VGPR/slot;
// VGPR must stay <= ~112 for 4 waves/SIMD — the R11/R13 cliff).
// Wave parity (wid&1): par0 -> offsets (0,0),(0,1),(0,2),(2,-2..2) [rows y,y+2]
//                      par1 -> offsets (1,-2..2)                   [rows y,y+1]
// Per channel par0 loads f4+f2 (row y) + f2+f4+f2 (row y+2) = 3584 B/wave;
// par1 f4 + f2+f4+f2 = 3072 B. Clamped edge loads only feed weight-0 terms.
// Grid: 1152 blocks x 256 (128 groups/block), XCD-chunk swizzled.
__global__ __launch_bounds__(256) void affinity_partial(
        const float* __restrict__ logits,
        const int* __restrict__ labels,
        float* __restrict__ partial) {
    const int t    = threadIdx.x;
    const int lane = t & 63;
    const int wid  = t >> 6;
    const int par  = wid & 1;

    const int b   = blockIdx.x;
    const int blk = (b & 7) * (NBLOCKS / 8) + (b >> 3);   // XCD chunking
    const int g   = blk * 128 + (wid >> 1) * 64 + lane;
    const int px0 = (g % 96) * 4;
    const int rs  = g / 96;
    const int py  = rs % H;
    const int n   = rs / H;

    const int x0c = max(0, px0 - 4);                 // 16B-aligned base col
    const int d1  = px0 - x0c;                       // 0 or 4
    const int c0  = max(px0 - 2, 0) - x0c;           // f2: cols px0-2,-1 (clamped)
    const int c2  = min(px0 + 4, W - 2) - x0c;       // f2: cols px0+4,+5 (clamped)
    const int ro1 = (min(py + 1, H - 1) - py) * W;
    const int ro2 = (min(py + 2, H - 1) - py) * W;

    const float* p0  = logits + (size_t)n * CHW + (size_t)py * W + x0c;
    const int*   lb0 = labels + (size_t)n * HW + (size_t)py * W + x0c;

    float total = 0.0f;

    if (par == 0) {
        float acc[32];
#pragma unroll
        for (int k = 0; k < 32; ++k) acc[k] = 0.0f;

        float4 sA1[3], sE1[3];
        float2 sA2[3], sE0[3], sE2[3];

#define P0L(ch, sl) {                                                     \
        const float* pr = p0 + (size_t)(ch) * HW;                         \
        sA1[sl] = *(const float4*)(pr + d1);                              \
        sA2[sl] = *(const float2*)(pr + c2);                              \
        sE0[sl] = *(const float2*)(pr + ro2 + c0);                        \
        sE1[sl] = *(const float4*)(pr + ro2 + d1);                        \
        sE2[sl] = *(const float2*)(pr + ro2 + c2); }

#define P0C(sl) {                                                         \
        const float a6[6] = {sA1[sl].x, sA1[sl].y, sA1[sl].z, sA1[sl].w,  \
                             sA2[sl].x, sA2[sl].y};                       \
        const float e8[8] = {sE0[sl].x, sE0[sl].y,                        \
                             sE1[sl].x, sE1[sl].y, sE1[sl].z, sE1[sl].w,  \
                             sE2[sl].x, sE2[sl].y};                       \
        _Pragma("unroll")                                                 \
        for (int i = 0; i < 4; ++i) {                                     \
            const float s = a6[i];                                        \
            acc[i * 8 + 0] += s * s;                                      \
            acc[i * 8 + 1] += s * a6[i + 1];                              \
            acc[i * 8 + 2] += s * a6[i + 2];                              \
            _Pragma("unroll")                                             \
            for (int dxi = 0; dxi < 5; ++dxi)                             \
                acc[i * 8 + 3 + dxi] += s * e8[i + dxi];                  \
        } }

        P0L(0, 0) P0L(1, 1)
#pragma unroll
        for (int st = 0; st < 19; ++st) {
            if (st + 2 < 19) { P0L(st + 2, (st + 2) % 3) }
            P0C(st % 3)
        }

        int la[6], ler[8];
        *(int4*)&la[0]  = *(const int4*)(lb0 + d1);
        *(int2*)&la[4]  = *(const int2*)(lb0 + c2);
        *(int2*)&ler[0] = *(const int2*)(lb0 + ro2 + c0);
        *(int4*)&ler[2] = *(const int4*)(lb0 + ro2 + d1);
        *(int2*)&ler[6] = *(const int2*)(lb0 + ro2 + c2);

        const int wy0 = multv(py, 0);
        const int wy2 = multv(py, 2);
#pragma unroll
        for (int i = 0; i < 4; ++i) {
            const int px = px0 + i;
            int wx[5];
#pragma unroll
            for (int dxi = 0; dxi < 5; ++dxi) wx[dxi] = multv(px, dxi - 2);
            const int ls = la[i];
            total += (float)(wy0 * wx[2]) * bce_fast(acc[i * 8 + 0], 1.0f);
            total += 2.0f * (float)(wy0 * wx[3]) *
                     bce_fast(acc[i * 8 + 1], (ls == la[i + 1]) ? 1.0f : 0.0f);
            total += 2.0f * (float)(wy0 * wx[4]) *
                     bce_fast(acc[i * 8 + 2], (ls == la[i + 2]) ? 1.0f : 0.0f);
#pragma unroll
            for (int dxi = 0; dxi < 5; ++dxi)
                total += 2.0f * (float)(wy2 * wx[dxi]) *
                         bce_fast(acc[i * 8 + 3 + dxi],
                                  (ls == ler[i + dxi]) ? 1.0f : 0.0f);
        }
    } else {
        float acc[20];
#pragma unroll
        for (int k = 0; k < 20; ++k) acc[k] = 0.0f;

        float4 sS[3], sB1[3];
        float2 sB0[3], sB2[3];

#define P1L(ch, sl) {                                                     \
        const float* pr = p0 + (size_t)(ch) * HW;                         \
        sS[sl]  = *(const float4*)(pr + d1);                              \
        sB0[sl] = *(const float2*)(pr + ro1 + c0);                        \
        sB1[sl] = *(const float4*)(pr + ro1 + d1);                        \
        sB2[sl] = *(const float2*)(pr + ro1 + c2); }

#define P1C(sl) {                                                         \
        const float b8[8] = {sB0[sl].x, sB0[sl].y,                        \
                             sB1[sl].x, sB1[sl].y, sB1[sl].z, sB1[sl].w,  \
                             sB2[sl].x, sB2[sl].y};                       \
        const float s4[4] = {sS[sl].x, sS[sl].y, sS[sl].z, sS[sl].w};     \
        _Pragma("unroll")                                                 \
        for (int i = 0; i < 4; ++i) {                                     \
            const float s = s4[i];                                        \
            _Pragma("unroll")                                             \
            for (int dxi = 0; dxi < 5; ++dxi)                             \
                acc[i * 5 + dxi] += s * b8[i + dxi];                      \
        } }

        P1L(0, 0) P1L(1, 1)
#pragma unroll
        for (int st = 0; st < 19; ++st) {
            if (st + 2 < 19) { P1L(st + 2, (st + 2) % 3) }
            P1C(st % 3)
        }

        int la4[4], lbr[8];
        *(int4*)&la4[0] = *(const int4*)(lb0 + d1);
        *(int2*)&lbr[0] = *(const int2*)(lb0 + ro1 + c0);
        *(int4*)&lbr[2] = *(const int4*)(lb0 + ro1 + d1);
        *(int2*)&lbr[6] = *(const int2*)(lb0 + ro1 + c2);

        const int wy1 = multv(py, 1);
#pragma unroll
        for (int i = 0; i < 4; ++i) {
            const int px = px0 + i;
            int wx[5];
#pragma unroll
            for (int dxi = 0; dxi < 5; ++dxi) wx[dxi] = multv(px, dxi - 2);
            const int ls = la4[i];
#pragma unroll
            for (int dxi = 0; dxi < 5; ++dxi)
                total += 2.0f * (float)(wy1 * wx[dxi]) *
                         bce_fast(acc[i * 5 + dxi],
                                  (ls == lbr[i + dxi]) ? 1.0f : 0.0f);
        }
    }

    // block reduction: wave shuffle then LDS across the 4 waves
#pragma unroll
    for (int off = 32; off > 0; off >>= 1) total += __shfl_down(total, off, 64);
    __shared__ float sm[4];
    if (lane == 0) sm[wid] = total;
    __syncthreads();
    if (t == 0)
        partial[blockIdx.x] = sm[0] + sm[1] + sm[2] + sm[3];
}

__global__ __launch_bounds__(256) void reduce_final(
        const float* __restrict__ partial, int n, float* __restrict__ out) {
    float s = 0.0f;
    for (int i = threadIdx.x; i < n; i += 256) s += partial[i];
#pragma unroll
    for (int off = 32; off > 0; off >>= 1) s += __shfl_down(s, off, 64);
    __shared__ float sm[4];
    const int lane = threadIdx.x & 63, wid = threadIdx.x >> 6;
    if (lane == 0) sm[wid] = s;
    __syncthreads();
    if (threadIdx.x == 0)
        out[0] = (sm[0] + sm[1] + sm[2] + sm[3]) / TOTAL_TERMS;
}

extern "C" void kernel_launch(void* const* d_in, const int* in_sizes, int n_in,
                              void* d_out, int out_size, void* d_ws, size_t ws_size,
                              hipStream_t stream) {
    const float* logits = (const float*)d_in[0];
    const int*   labels = (const int*)d_in[1];
    float* out     = (float*)d_out;
    float* partial = (float*)d_ws;   // 1152 floats

    affinity_partial<<<NBLOCKS, 256, 0, stream>>>(logits, labels, partial);
    reduce_final<<<1, 256, 0, stream>>>(partial, NBLOCKS, out);
}

// Round 15
// 39.749 us; speedup vs baseline: 1.2369x; 1.2369x over previous
//
#include <hip/hip_runtime.h>

#define H 384
#define W 384
#define C 19
#define NB 4
#define HP 382               // H - K + 1
#define HW (H * W)
#define CHW (C * HW)
#define TOTAL_TERMS 47279376.0f   // NB * 81 * HP*HP

#define NBLOCKS 1152         // 4 images * 96 row-bands * 3 col-tiles

// number of kernel-offsets a in [0,2] with 0 <= a+d <= 2 and 0 <= p-a <= HP-1
__device__ __forceinline__ int multv(int p, int d) {
    int lo = max(max(0, -d), p - (HP - 1));
    int hi = min(min(2, 2 - d), p);
    return max(0, hi - lo + 1);
}

__device__ __forceinline__ float bce_fast(float x, float y) {
    // max(x,0) - x*y + log1p(exp(-|x|)), fast-math variant
    float t = __expf(-fabsf(x));
    return fmaxf(x, 0.0f) - x * y + __logf(1.0f + t);
}

// R12 skeleton (depth-2, 3-slot f4-only register pipeline — 28.4 µs proven),
// ONE change: block->pixel mapping. Each block now owns a 128-px x 4-row
// tile (sub = 32 x-groups x 4 rows) instead of 1.33 full-width rows, so the
// dy=0/1/2 row-halo reuse happens INSIDE the block's L1 (per-channel working
// set ~3.3 KB vs ~18 KB of L2 traffic before). Loop bodies byte-identical to
// R12 (f4-only loads — the 132-VGPR f2-trim codegen of R13/R14 is poison).
// Grid: 1152 blocks x 256, XCD-chunk swizzled (adjacent bands same XCD).
__global__ __launch_bounds__(256) void affinity_partial(
        const float* __restrict__ logits,
        const int* __restrict__ labels,
        float* __restrict__ partial) {
    const int t    = threadIdx.x;
    const int lane = t & 63;
    const int wid  = t >> 6;
    const int par  = wid & 1;

    const int b   = blockIdx.x;
    const int blk = (b & 7) * (NBLOCKS / 8) + (b >> 3);   // XCD chunking
    const int sub = (wid >> 1) * 64 + lane;               // [0,128)
    const int bx  = sub & 31;                             // x-group in tile
    const int by  = sub >> 5;                             // row in tile [0,4)
    const int n    = blk / 288;
    const int rem  = blk % 288;
    const int band = rem / 3;
    const int bcol = rem % 3;
    const int py  = band * 4 + by;
    const int px0 = (bcol * 32 + bx) * 4;

    // f4 at +d1 -> cols px0..px0+3, +d2 -> px0+4..+7, +0 -> px0-4..-1.
    // Degenerate edge slots only feed weight-0 terms (multv==0 off-image).
    const int x0c = max(0, px0 - 4);
    const int d1  = px0 - x0c;                 // 0 or 4
    const int d2  = min(W - 4, px0 + 4) - x0c; // 4 or 8 (==d1 at right edge)
    const int ro1 = (min(py + 1, H - 1) - py) * W;
    const int ro2 = (min(py + 2, H - 1) - py) * W;

    const float* p0  = logits + (size_t)n * CHW + (size_t)py * W + x0c;
    const int*   lb0 = labels + (size_t)n * HW + (size_t)py * W + x0c;

    float total = 0.0f;

    if (par == 0) {
        float acc[32];
#pragma unroll
        for (int k = 0; k < 32; ++k) acc[k] = 0.0f;

        float4 sA1[3], sA2[3], sE0[3], sE1[3], sE2[3];

#define P0L(ch, sl) {                                                     \
        const float* pr = p0 + (size_t)(ch) * HW;                         \
        sA1[sl] = *(const float4*)(pr + d1);                              \
        sA2[sl] = *(const float4*)(pr + d2);                              \
        sE0[sl] = *(const float4*)(pr + ro2);                             \
        sE1[sl] = *(const float4*)(pr + ro2 + d1);                        \
        sE2[sl] = *(const float4*)(pr + ro2 + d2); }

#define P0C(sl) {                                                         \
        const float a6[6] = {sA1[sl].x, sA1[sl].y, sA1[sl].z, sA1[sl].w,  \
                             sA2[sl].x, sA2[sl].y};                       \
        const float e8[8] = {sE0[sl].z, sE0[sl].w,                        \
                             sE1[sl].x, sE1[sl].y, sE1[sl].z, sE1[sl].w,  \
                             sE2[sl].x, sE2[sl].y};                       \
        _Pragma("unroll")                                                 \
        for (int i = 0; i < 4; ++i) {                                     \
            const float s = a6[i];                                        \
            acc[i * 8 + 0] += s * s;                                      \
            acc[i * 8 + 1] += s * a6[i + 1];                              \
            acc[i * 8 + 2] += s * a6[i + 2];                              \
            _Pragma("unroll")                                             \
            for (int dxi = 0; dxi < 5; ++dxi)                             \
                acc[i * 8 + 3 + dxi] += s * e8[i + dxi];                  \
        } }

        P0L(0, 0) P0L(1, 1)
#pragma unroll
        for (int st = 0; st < 19; ++st) {
            if (st + 2 < 19) { P0L(st + 2, (st + 2) % 3) }
            P0C(st % 3)
        }

        int la[8], ler[12];
        *(int4*)&la[0]  = *(const int4*)(lb0 + d1);   // cols px0..px0+3
        *(int4*)&la[4]  = *(const int4*)(lb0 + d2);   // cols px0+4..px0+7
        *(int4*)&ler[0] = *(const int4*)(lb0 + ro2);
        *(int4*)&ler[4] = *(const int4*)(lb0 + ro2 + d1);
        *(int4*)&ler[8] = *(const int4*)(lb0 + ro2 + d2);

        const int wy0 = multv(py, 0);
        const int wy2 = multv(py, 2);
#pragma unroll
        for (int i = 0; i < 4; ++i) {
            const int px = px0 + i;
            int wx[5];
#pragma unroll
            for (int dxi = 0; dxi < 5; ++dxi) wx[dxi] = multv(px, dxi - 2);
            const int ls = la[i];
            total += (float)(wy0 * wx[2]) * bce_fast(acc[i * 8 + 0], 1.0f);
            total += 2.0f * (float)(wy0 * wx[3]) *
                     bce_fast(acc[i * 8 + 1], (ls == la[i + 1]) ? 1.0f : 0.0f);
            total += 2.0f * (float)(wy0 * wx[4]) *
                     bce_fast(acc[i * 8 + 2], (ls == la[i + 2]) ? 1.0f : 0.0f);
#pragma unroll
            for (int dxi = 0; dxi < 5; ++dxi)
                total += 2.0f * (float)(wy2 * wx[dxi]) *
                         bce_fast(acc[i * 8 + 3 + dxi],
                                  (ls == ler[2 + i + dxi]) ? 1.0f : 0.0f);
        }
    } else {
        float acc[20];
#pragma unroll
        for (int k = 0; k < 20; ++k) acc[k] = 0.0f;

        float4 sS[3], sB0[3], sB1[3], sB2[3];

#define P1L(ch, sl) {                                                     \
        const float* pr = p0 + (size_t)(ch) * HW;                         \
        sS[sl]  = *(const float4*)(pr + d1);                              \
        sB0[sl] = *(const float4*)(pr + ro1);                             \
        sB1[sl] = *(const float4*)(pr + ro1 + d1);                        \
        sB2[sl] = *(const float4*)(pr + ro1 + d2); }

#define P1C(sl) {                                                         \
        const float b8[8] = {sB0[sl].z, sB0[sl].w,                        \
                             sB1[sl].x, sB1[sl].y, sB1[sl].z, sB1[sl].w,  \
                             sB2[sl].x, sB2[sl].y};                       \
        const float s4[4] = {sS[sl].x, sS[sl].y, sS[sl].z, sS[sl].w};     \
        _Pragma("unroll")                                                 \
        for (int i = 0; i < 4; ++i) {                                     \
            const float s = s4[i];                                        \
            _Pragma("unroll")                                             \
            for (int dxi = 0; dxi < 5; ++dxi)                             \
                acc[i * 5 + dxi] += s * b8[i + dxi];                      \
        } }

        P1L(0, 0) P1L(1, 1)
#pragma unroll
        for (int st = 0; st < 19; ++st) {
            if (st + 2 < 19) { P1L(st + 2, (st + 2) % 3) }
            P1C(st % 3)
        }

        int la4[4], lbr[12];
        *(int4*)&la4[0] = *(const int4*)(lb0 + d1);
        *(int4*)&lbr[0] = *(const int4*)(lb0 + ro1);
        *(int4*)&lbr[4] = *(const int4*)(lb0 + ro1 + d1);
        *(int4*)&lbr[8] = *(const int4*)(lb0 + ro1 + d2);

        const int wy1 = multv(py, 1);
#pragma unroll
        for (int i = 0; i < 4; ++i) {
            const int px = px0 + i;
            int wx[5];
#pragma unroll
            for (int dxi = 0; dxi < 5; ++dxi) wx[dxi] = multv(px, dxi - 2);
            const int ls = la4[i];
#pragma unroll
            for (int dxi = 0; dxi < 5; ++dxi)
                total += 2.0f * (float)(wy1 * wx[dxi]) *
                         bce_fast(acc[i * 5 + dxi],
                                  (ls == lbr[2 + i + dxi]) ? 1.0f : 0.0f);
        }
    }

    // block reduction: wave shuffle then LDS across the 4 waves
#pragma unroll
    for (int off = 32; off > 0; off >>= 1) total += __shfl_down(total, off, 64);
    __shared__ float sm[4];
    if (lane == 0) sm[wid] = total;
    __syncthreads();
    if (t == 0)
        partial[blockIdx.x] = sm[0] + sm[1] + sm[2] + sm[3];
}

__global__ __launch_bounds__(256) void reduce_final(
        const float* __restrict__ partial, int n, float* __restrict__ out) {
    float s = 0.0f;
    for (int i = threadIdx.x; i < n; i += 256) s += partial[i];
#pragma unroll
    for (int off = 32; off > 0; off >>= 1) s += __shfl_down(s, off, 64);
    __shared__ float sm[4];
    const int lane = threadIdx.x & 63, wid = threadIdx.x >> 6;
    if (lane == 0) sm[wid] = s;
    __syncthreads();
    if (threadIdx.x == 0)
        out[0] = (sm[0] + sm[1] + sm[2] + sm[3]) / TOTAL_TERMS;
}

extern "C" void kernel_launch(void* const* d_in, const int* in_sizes, int n_in,
                              void* d_out, int out_size, void* d_ws, size_t ws_size,
                              hipStream_t stream) {
    const float* logits = (const float*)d_in[0];
    const int*   labels = (const int*)d_in[1];
    float* out     = (float*)d_out;
    float* partial = (float*)d_ws;   // 1152 floats

    affinity_partial<<<NBLOCKS, 256, 0, stream>>>(logits, labels, partial);
    reduce_final<<<1, 256, 0, stream>>>(partial, NBLOCKS, out);
}

// Round 16
// 37.418 us; speedup vs baseline: 1.3140x; 1.0623x over previous
//
#include <hip/hip_runtime.h>

#define H 384
#define W 384
#define C 19
#define NB 4
#define HP 382               // H - K + 1
#define HW (H * W)
#define CHW (C * HW)
#define TOTAL_TERMS 47279376.0f   // NB * 81 * HP*HP

#define NBLOCKS 1152         // 147456 groups / 128

// number of kernel-offsets a in [0,2] with 0 <= a+d <= 2 and 0 <= p-a <= HP-1
__device__ __forceinline__ int multv(int p, int d) {
    int lo = max(max(0, -d), p - (HP - 1));
    int hi = min(min(2, 2 - d), p);
    return max(0, hi - lo + 1);
}

__device__ __forceinline__ float bce_fast(float x, float y) {
    // max(x,0) - x*y + log1p(exp(-|x|)), fast-math variant
    float t = __expf(-fabsf(x));
    return fmaxf(x, 0.0f) - x * y + __logf(1.0f + t);
}

// R12 skeleton EXACTLY (depth-2, 3-slot, f4-only register pipeline, full-width
// row-major group mapping, XCD chunking — 28.4 µs proven). ONE change: the
// reduce_final kernel is deleted; out[0] is zeroed by a 4-byte memset node
// and each block atomicAdds its pre-scaled partial (device-scope, fine
// across XCDs). Saves one kernel launch + 1-block reduction latency.
__global__ __launch_bounds__(256) void affinity_partial(
        const float* __restrict__ logits,
        const int* __restrict__ labels,
        float* __restrict__ out) {
    const int t    = threadIdx.x;
    const int lane = t & 63;
    const int wid  = t >> 6;
    const int par  = wid & 1;

    const int b   = blockIdx.x;
    const int blk = (b & 7) * (NBLOCKS / 8) + (b >> 3);   // XCD chunking
    const int g   = blk * 128 + (wid >> 1) * 64 + lane;
    const int px0 = (g % 96) * 4;
    const int rs  = g / 96;
    const int py  = rs % H;
    const int n   = rs / H;

    // f4 at +d1 -> cols px0..px0+3, +d2 -> px0+4..+7, +0 -> px0-4..-1.
    // Degenerate edge slots only feed weight-0 terms (multv==0 off-image).
    const int x0c = max(0, px0 - 4);
    const int d1  = px0 - x0c;                 // 0 or 4
    const int d2  = min(W - 4, px0 + 4) - x0c; // 4 or 8 (==d1 at right edge)
    const int ro1 = (min(py + 1, H - 1) - py) * W;
    const int ro2 = (min(py + 2, H - 1) - py) * W;

    const float* p0  = logits + (size_t)n * CHW + (size_t)py * W + x0c;
    const int*   lb0 = labels + (size_t)n * HW + (size_t)py * W + x0c;

    float total = 0.0f;

    if (par == 0) {
        float acc[32];
#pragma unroll
        for (int k = 0; k < 32; ++k) acc[k] = 0.0f;

        float4 sA1[3], sA2[3], sE0[3], sE1[3], sE2[3];

#define P0L(ch, sl) {                                                     \
        const float* pr = p0 + (size_t)(ch) * HW;                         \
        sA1[sl] = *(const float4*)(pr + d1);                              \
        sA2[sl] = *(const float4*)(pr + d2);                              \
        sE0[sl] = *(const float4*)(pr + ro2);                             \
        sE1[sl] = *(const float4*)(pr + ro2 + d1);                        \
        sE2[sl] = *(const float4*)(pr + ro2 + d2); }

#define P0C(sl) {                                                         \
        const float a6[6] = {sA1[sl].x, sA1[sl].y, sA1[sl].z, sA1[sl].w,  \
                             sA2[sl].x, sA2[sl].y};                       \
        const float e8[8] = {sE0[sl].z, sE0[sl].w,                        \
                             sE1[sl].x, sE1[sl].y, sE1[sl].z, sE1[sl].w,  \
                             sE2[sl].x, sE2[sl].y};                       \
        _Pragma("unroll")                                                 \
        for (int i = 0; i < 4; ++i) {                                     \
            const float s = a6[i];                                        \
            acc[i * 8 + 0] += s * s;                                      \
            acc[i * 8 + 1] += s * a6[i + 1];                              \
            acc[i * 8 + 2] += s * a6[i + 2];                              \
            _Pragma("unroll")                                             \
            for (int dxi = 0; dxi < 5; ++dxi)                             \
                acc[i * 8 + 3 + dxi] += s * e8[i + dxi];                  \
        } }

        P0L(0, 0) P0L(1, 1)
#pragma unroll
        for (int st = 0; st < 19; ++st) {
            if (st + 2 < 19) { P0L(st + 2, (st + 2) % 3) }
            P0C(st % 3)
        }

        int la[8], ler[12];
        *(int4*)&la[0]  = *(const int4*)(lb0 + d1);   // cols px0..px0+3
        *(int4*)&la[4]  = *(const int4*)(lb0 + d2);   // cols px0+4..px0+7
        *(int4*)&ler[0] = *(const int4*)(lb0 + ro2);
        *(int4*)&ler[4] = *(const int4*)(lb0 + ro2 + d1);
        *(int4*)&ler[8] = *(const int4*)(lb0 + ro2 + d2);

        const int wy0 = multv(py, 0);
        const int wy2 = multv(py, 2);
#pragma unroll
        for (int i = 0; i < 4; ++i) {
            const int px = px0 + i;
            int wx[5];
#pragma unroll
            for (int dxi = 0; dxi < 5; ++dxi) wx[dxi] = multv(px, dxi - 2);
            const int ls = la[i];
            total += (float)(wy0 * wx[2]) * bce_fast(acc[i * 8 + 0], 1.0f);
            total += 2.0f * (float)(wy0 * wx[3]) *
                     bce_fast(acc[i * 8 + 1], (ls == la[i + 1]) ? 1.0f : 0.0f);
            total += 2.0f * (float)(wy0 * wx[4]) *
                     bce_fast(acc[i * 8 + 2], (ls == la[i + 2]) ? 1.0f : 0.0f);
#pragma unroll
            for (int dxi = 0; dxi < 5; ++dxi)
                total += 2.0f * (float)(wy2 * wx[dxi]) *
                         bce_fast(acc[i * 8 + 3 + dxi],
                                  (ls == ler[2 + i + dxi]) ? 1.0f : 0.0f);
        }
    } else {
        float acc[20];
#pragma unroll
        for (int k = 0; k < 20; ++k) acc[k] = 0.0f;

        float4 sS[3], sB0[3], sB1[3], sB2[3];

#define P1L(ch, sl) {                                                     \
        const float* pr = p0 + (size_t)(ch) * HW;                         \
        sS[sl]  = *(const float4*)(pr + d1);                              \
        sB0[sl] = *(const float4*)(pr + ro1);                             \
        sB1[sl] = *(const float4*)(pr + ro1 + d1);                        \
        sB2[sl] = *(const float4*)(pr + ro1 + d2); }

#define P1C(sl) {                                                         \
        const float b8[8] = {sB0[sl].z, sB0[sl].w,                        \
                             sB1[sl].x, sB1[sl].y, sB1[sl].z, sB1[sl].w,  \
                             sB2[sl].x, sB2[sl].y};                       \
        const float s4[4] = {sS[sl].x, sS[sl].y, sS[sl].z, sS[sl].w};     \
        _Pragma("unroll")                                                 \
        for (int i = 0; i < 4; ++i) {                                     \
            const float s = s4[i];                                        \
            _Pragma("unroll")                                             \
            for (int dxi = 0; dxi < 5; ++dxi)                             \
                acc[i * 5 + dxi] += s * b8[i + dxi];                      \
        } }

        P1L(0, 0) P1L(1, 1)
#pragma unroll
        for (int st = 0; st < 19; ++st) {
            if (st + 2 < 19) { P1L(st + 2, (st + 2) % 3) }
            P1C(st % 3)
        }

        int la4[4], lbr[12];
        *(int4*)&la4[0] = *(const int4*)(lb0 + d1);
        *(int4*)&lbr[0] = *(const int4*)(lb0 + ro1);
        *(int4*)&lbr[4] = *(const int4*)(lb0 + ro1 + d1);
        *(int4*)&lbr[8] = *(const int4*)(lb0 + ro1 + d2);

        const int wy1 = multv(py, 1);
#pragma unroll
        for (int i = 0; i < 4; ++i) {
            const int px = px0 + i;
            int wx[5];
#pragma unroll
            for (int dxi = 0; dxi < 5; ++dxi) wx[dxi] = multv(px, dxi - 2);
            const int ls = la4[i];
#pragma unroll
            for (int dxi = 0; dxi < 5; ++dxi)
                total += 2.0f * (float)(wy1 * wx[dxi]) *
                         bce_fast(acc[i * 5 + dxi],
                                  (ls == lbr[2 + i + dxi]) ? 1.0f : 0.0f);
        }
    }

    // block reduction: wave shuffle then LDS across the 4 waves
#pragma unroll
    for (int off = 32; off > 0; off >>= 1) total += __shfl_down(total, off, 64);
    __shared__ float sm[4];
    if (lane == 0) sm[wid] = total;
    __syncthreads();
    if (t == 0)
        atomicAdd(out, (sm[0] + sm[1] + sm[2] + sm[3]) * (1.0f / TOTAL_TERMS));
}

extern "C" void kernel_launch(void* const* d_in, const int* in_sizes, int n_in,
                              void* d_out, int out_size, void* d_ws, size_t ws_size,
                              hipStream_t stream) {
    const float* logits = (const float*)d_in[0];
    const int*   labels = (const int*)d_in[1];
    float* out = (float*)d_out;

    hipMemsetAsync(out, 0, sizeof(float), stream);
    affinity_partial<<<NBLOCKS, 256, 0, stream>>>(logits, labels, out);
}